// Round 2
// baseline (69.020 us; speedup 1.0000x reference)
//
#include <hip/hip_runtime.h>
#include <math.h>

// Problem geometry (from reference):
//   p3: locs grid i in [0,152) (y), j in [0,100) (x), stride 8  -> 45600 anchors
//   p4: i in [0,76), j in [0,50),  stride 16 -> 11400 anchors
//   p5: i in [0,38), j in [0,25),  stride 32 ->  2850 anchors
// anchor index within level: ((i*Hx + j)*3 + r), Hx = j-count
// outputs flat: boxes[59850*4] | anchors[59850*4] | max_iou[59850]
#define NTOT     59850
#define NPROP    2000
#define ANCH_OFF 239400   // floats
#define MIOU_OFF 478800   // floats

struct BuildConsts {
    float hw[3][3];   // half-width  [level][aspect]
    float hh[3][3];   // half-height [level][aspect]
    float clampv;     // log(224/8)
};

__global__ __launch_bounds__(256) void build_kernel(
    const float4* __restrict__ d3,
    const float4* __restrict__ d4,
    const float4* __restrict__ d5,
    float* __restrict__ out,
    BuildConsts C)
{
    int g = blockIdx.x * 256 + threadIdx.x;
    if (g >= NTOT) return;

    int level, a, H, s;
    const float4* dl;
    if (g < 45600)      { level = 0; a = g;         H = 100; s = 8;  dl = d3; }
    else if (g < 57000) { level = 1; a = g - 45600; H = 50;  s = 16; dl = d4; }
    else                { level = 2; a = g - 57000; H = 25;  s = 32; dl = d5; }

    int loc = a / 3;
    int r   = a - loc * 3;
    int i   = loc / H;       // y index
    int j   = loc - i * H;   // x index
    float x = (float)s * ((float)j + 0.5f);
    float y = (float)s * ((float)i + 0.5f);

    float hwv = C.hw[level][r], hhv = C.hh[level][r];
    float ax0 = x - hwv, ay0 = y - hhv;
    float ax1 = x + hwv, ay1 = y + hhv;

    float4 d = dl[a];
    float w  = ax1 - ax0, h = ay1 - ay0;
    float cx = (ax0 + ax1) * 0.5f, cy = (ay0 + ay1) * 0.5f;
    float dwx = fminf(d.z, C.clampv), dwy = fminf(d.w, C.clampv);
    float ncx = cx + w * d.x, ncy = cy + h * d.y;
    float nw  = w * expf(dwx), nh = h * expf(dwy);

    ((float4*)out)[g] = make_float4(ncx - 0.5f * nw, ncy - 0.5f * nh,
                                    ncx + 0.5f * nw, ncy + 0.5f * nh);
    ((float4*)(out + ANCH_OFF))[g] = make_float4(ax0, ay0, ax1, ay1);
    out[MIOU_OFF + g] = 0.0f;   // re-zero every call (replays don't re-poison)
}

// grid (2000, 9): x = proposal id, y = (level*3 + aspect) combo.
// Each block scatters exact IoU to the anchors its proposal can overlap.
__global__ __launch_bounds__(64) void scatter_kernel(
    const float4* __restrict__ boxes,   // proposals = first 2000 boxes
    float* __restrict__ miou,
    BuildConsts C)
{
    const int Hx[3]    = {100, 50, 25};    // j-count (x)
    const int Wy[3]    = {152, 76, 38};    // i-count (y)
    const float sv[3]  = {8.f, 16.f, 32.f};
    const int baseL[3] = {0, 45600, 57000};

    int combo = blockIdx.y;
    int lev   = combo / 3;
    int r     = combo - lev * 3;

    float4 b = boxes[blockIdx.x];          // wave-uniform
    float pa = (b.z - b.x) * (b.w - b.y);

    float s = sv[lev], inv_s = 1.0f / s;
    float hw = C.hw[lev][r], hh = C.hh[lev][r];
    float a2 = 4.0f * hw * hh;
    int hx = Hx[lev];

    // conservative anchor-center range with nonzero overlap (±1 slack is free:
    // boundary anchors give inter==0 and are skipped)
    int jlo = max(0,      (int)floorf((b.x - hw) * inv_s - 0.5f));
    int jhi = min(hx - 1, (int)ceilf ((b.z + hw) * inv_s - 0.5f));
    int ilo = max(0,          (int)floorf((b.y - hh) * inv_s - 0.5f));
    int ihi = min(Wy[lev] - 1, (int)ceilf ((b.w + hh) * inv_s - 0.5f));
    int nj = jhi - jlo + 1, ni = ihi - ilo + 1;
    if (nj <= 0 || ni <= 0) return;
    int cnt = ni * nj;

    for (int t = threadIdx.x; t < cnt; t += 64) {
        int i = t / nj;
        int j = t - i * nj;
        i += ilo; j += jlo;
        float x = s * ((float)j + 0.5f);
        float y = s * ((float)i + 0.5f);
        float xl = fmaxf(b.x, x - hw), yl = fmaxf(b.y, y - hh);
        float xr = fminf(b.z, x + hw), yr = fminf(b.w, y + hh);
        float iw = fmaxf(xr - xl, 0.0f), ih = fmaxf(yr - yl, 0.0f);
        float inter = iw * ih;
        if (inter > 0.0f) {
            float v = inter / (pa + a2 - inter);
            int idx = baseL[lev] + (i * hx + j) * 3 + r;
            // IoU >= 0: uint compare == float compare; max is order-independent
            atomicMax((unsigned int*)(miou + idx), __float_as_uint(v));
        }
    }
}

extern "C" void kernel_launch(void* const* d_in, const int* in_sizes, int n_in,
                              void* d_out, int out_size, void* d_ws, size_t ws_size,
                              hipStream_t stream) {
    // inputs: 0..2 = feats (unused), 3..5 = deltas p3/p4/p5
    const float4* d3 = (const float4*)d_in[3];
    const float4* d4 = (const float4*)d_in[4];
    const float4* d5 = (const float4*)d_in[5];
    float* out = (float*)d_out;

    BuildConsts C;
    const double sArr[3]  = {8.0, 16.0, 32.0};
    const double arArr[3] = {0.5, 1.0, 2.0};
    for (int l = 0; l < 3; ++l) {
        double as   = 4.0 * sArr[l];
        double area = as * as;
        for (int rr = 0; rr < 3; ++rr) {
            double w = sqrt(area / arArr[rr]);
            double h = area / w;
            C.hw[l][rr] = (float)w * 0.5f;
            C.hh[l][rr] = (float)h * 0.5f;
        }
    }
    C.clampv = (float)log(224.0 / 8.0);

    build_kernel<<<dim3((NTOT + 255) / 256), 256, 0, stream>>>(d3, d4, d5, out, C);
    // stream order guarantees build (incl. miou zeroing) completes first
    scatter_kernel<<<dim3(NPROP, 9), 64, 0, stream>>>(
        (const float4*)out, out + MIOU_OFF, C);
}

// Round 3
// 36.266 us; speedup vs baseline: 1.9032x; 1.9032x over previous
//
#include <hip/hip_runtime.h>
#include <math.h>

// Problem geometry (from reference):
//   p3: x-count 100, y-count 152, stride 8  -> 45600 anchors
//   p4: x-count 50,  y-count 76,  stride 16 -> 11400 anchors
//   p5: x-count 25,  y-count 38,  stride 32 ->  2850 anchors
// within-level anchor index: ((i*Hx + j)*3 + r), i = y idx, j = x idx
// outputs flat: boxes[59850*4] | anchors[59850*4] | max_iou[59850]
#define NTOT     59850
#define NPROP    2000
#define ANCH_OFF 239400   // floats
#define MIOU_OFF 478800   // floats
#define NCHUNK   32
#define CS       64       // 32*64 = 2048 >= 2000 (indices clamped)

struct BuildConsts {
    float hw[3][3];   // half-width  [level][aspect]
    float hh[3][3];   // half-height [level][aspect]
    float clampv;     // log(224/8)
};

__global__ __launch_bounds__(256) void build_kernel(
    const float4* __restrict__ d3,
    const float4* __restrict__ d4,
    const float4* __restrict__ d5,
    float* __restrict__ out,
    BuildConsts C)
{
    int g = blockIdx.x * 256 + threadIdx.x;
    if (g >= NTOT) return;

    int level, a, H, s;
    const float4* dl;
    if (g < 45600)      { level = 0; a = g;         H = 100; s = 8;  dl = d3; }
    else if (g < 57000) { level = 1; a = g - 45600; H = 50;  s = 16; dl = d4; }
    else                { level = 2; a = g - 57000; H = 25;  s = 32; dl = d5; }

    int loc = a / 3;
    int r   = a - loc * 3;
    int i   = loc / H;       // y index
    int j   = loc - i * H;   // x index
    float x = (float)s * ((float)j + 0.5f);
    float y = (float)s * ((float)i + 0.5f);

    float hwv = C.hw[level][r], hhv = C.hh[level][r];
    float ax0 = x - hwv, ay0 = y - hhv;
    float ax1 = x + hwv, ay1 = y + hhv;

    float4 d = dl[a];
    float w  = ax1 - ax0, h = ay1 - ay0;
    float cx = (ax0 + ax1) * 0.5f, cy = (ay0 + ay1) * 0.5f;
    float dwx = fminf(d.z, C.clampv), dwy = fminf(d.w, C.clampv);
    float ncx = cx + w * d.x, ncy = cy + h * d.y;
    float nw  = w * expf(dwx), nh = h * expf(dwy);

    ((float4*)out)[g] = make_float4(ncx - 0.5f * nw, ncy - 0.5f * nh,
                                    ncx + 0.5f * nw, ncy + 0.5f * nh);
    ((float4*)(out + ANCH_OFF))[g] = make_float4(ax0, ay0, ax1, ay1);
    out[MIOU_OFF + g] = 0.0f;   // re-zero every call (replays don't re-poison)
}

// single block: union bbox of the 2000 proposals -> d_ws
__global__ __launch_bounds__(256) void bbox_kernel(
    const float4* __restrict__ boxes, float4* __restrict__ bbox_out)
{
    __shared__ float4 red[256];
    float4 m = make_float4(1e30f, 1e30f, -1e30f, -1e30f);
    for (int t = threadIdx.x; t < NPROP; t += 256) {
        float4 b = boxes[t];
        m.x = fminf(m.x, b.x); m.y = fminf(m.y, b.y);
        m.z = fmaxf(m.z, b.z); m.w = fmaxf(m.w, b.w);
    }
    red[threadIdx.x] = m;
    __syncthreads();
    for (int s2 = 128; s2 > 0; s2 >>= 1) {
        if (threadIdx.x < s2) {
            float4 o = red[threadIdx.x + s2];
            float4 c = red[threadIdx.x];
            c.x = fminf(c.x, o.x); c.y = fminf(c.y, o.y);
            c.z = fmaxf(c.z, o.z); c.w = fmaxf(c.w, o.w);
            red[threadIdx.x] = c;
        }
        __syncthreads();
    }
    if (threadIdx.x == 0) *bbox_out = red[0];
}

// grid (59, 32): x covers 59*1024 anchors (4/thread), y = proposal chunk of 64.
// Blocks whose 1024 anchors don't touch the proposal-union bbox exit early.
__global__ __launch_bounds__(256) void iou_kernel(
    const float4* __restrict__ props,
    const float4* __restrict__ anch,
    const float4* __restrict__ bbox_p,   // in d_ws
    float* __restrict__ miou)
{
    __shared__ float4 Pb[CS];
    __shared__ float  Pa[CS];

    int tid  = threadIdx.x;
    int base = blockIdx.x * 1024 + tid;
    float4 bb = *bbox_p;

    float ax0[4], ay0[4], ax1[4], ay1[4], a2[4], Ib[4], Sb[4];
    bool  live[4];
    bool  any = false;
    #pragma unroll
    for (int k = 0; k < 4; ++k) {
        int g = base + k * 256;
        bool valid = (g < NTOT);
        float4 A = anch[valid ? g : 0];
        ax0[k] = A.x; ay0[k] = A.y; ax1[k] = A.z; ay1[k] = A.w;
        a2[k]  = (A.z - A.x) * (A.w - A.y);
        Ib[k]  = 0.0f; Sb[k] = 1.0f;
        live[k] = valid && (A.x <= bb.z) && (A.z >= bb.x)
                        && (A.y <= bb.w) && (A.w >= bb.y);
        any = any || live[k];
    }
    if (!__syncthreads_or((int)any)) return;   // whole block dead

    if (tid < CS) {
        int p = blockIdx.y * CS + tid;
        p = p < NPROP ? p : NPROP - 1;          // clamp: duplicate is harmless for max
        float4 b = props[p];
        Pb[tid] = b;
        Pa[tid] = (b.z - b.x) * (b.w - b.y);
    }
    __syncthreads();

    if (any) {
        #pragma unroll 2
        for (int p = 0; p < CS; ++p) {
            float4 b  = Pb[p];   // broadcast read, conflict-free
            float  pa = Pa[p];
            #pragma unroll
            for (int k = 0; k < 4; ++k) {
                float xl = fmaxf(b.x, ax0[k]);
                float yl = fmaxf(b.y, ay0[k]);
                float xr = fminf(b.z, ax1[k]);
                float yr = fminf(b.w, ay1[k]);
                float iw = fmaxf(xr - xl, 0.0f);
                float ih = fmaxf(yr - yl, 0.0f);
                float inter = iw * ih;
                float S = pa + a2[k];
                // IoU_a > IoU_b  <=>  Ia*Sb > Ib*Sa  (S = sum of areas, union > 0)
                bool better = inter * Sb[k] > Ib[k] * S;
                Ib[k] = better ? inter : Ib[k];
                Sb[k] = better ? S     : Sb[k];
            }
        }
    }

    #pragma unroll
    for (int k = 0; k < 4; ++k) {
        if (live[k] && Ib[k] > 0.0f) {
            float m = Ib[k] / (Sb[k] - Ib[k]);
            // IoU >= 0: uint compare == float compare; max is order-independent
            atomicMax((unsigned int*)(miou + base + k * 256), __float_as_uint(m));
        }
    }
}

extern "C" void kernel_launch(void* const* d_in, const int* in_sizes, int n_in,
                              void* d_out, int out_size, void* d_ws, size_t ws_size,
                              hipStream_t stream) {
    // inputs: 0..2 = feats (unused), 3..5 = deltas p3/p4/p5
    const float4* d3 = (const float4*)d_in[3];
    const float4* d4 = (const float4*)d_in[4];
    const float4* d5 = (const float4*)d_in[5];
    float* out = (float*)d_out;

    BuildConsts C;
    const double sArr[3]  = {8.0, 16.0, 32.0};
    const double arArr[3] = {0.5, 1.0, 2.0};
    for (int l = 0; l < 3; ++l) {
        double as   = 4.0 * sArr[l];
        double area = as * as;
        for (int rr = 0; rr < 3; ++rr) {
            double w = sqrt(area / arArr[rr]);
            double h = area / w;
            C.hw[l][rr] = (float)w * 0.5f;
            C.hh[l][rr] = (float)h * 0.5f;
        }
    }
    C.clampv = (float)log(224.0 / 8.0);

    build_kernel<<<dim3((NTOT + 255) / 256), 256, 0, stream>>>(d3, d4, d5, out, C);
    bbox_kernel<<<dim3(1), 256, 0, stream>>>((const float4*)out, (float4*)d_ws);
    iou_kernel<<<dim3(59, NCHUNK), 256, 0, stream>>>(
        (const float4*)out, (const float4*)(out + ANCH_OFF),
        (const float4*)d_ws, out + MIOU_OFF);
}

// Round 4
// 33.339 us; speedup vs baseline: 2.0703x; 1.0878x over previous
//
#include <hip/hip_runtime.h>
#include <math.h>

// Problem geometry (from reference):
//   p3: x-count 100, y-count 152, stride 8  -> 45600 anchors
//   p4: x-count 50,  y-count 76,  stride 16 -> 11400 anchors
//   p5: x-count 25,  y-count 38,  stride 32 ->  2850 anchors
// within-level anchor index: ((i*hx + j)*3 + r), i = y idx, j = x idx
// outputs flat: boxes[59850*4] | anchors[59850*4] | max_iou[59850]
#define NTOT     59850
#define NPROP    2000
#define ANCH_OFF 239400   // floats
#define MIOU_OFF 478800   // floats
#define NCHUNK   32
#define CS       64       // 32*64 = 2048 >= 2000 (indices clamped)

struct BuildConsts {
    float hw[3][3];   // half-width  [level][aspect]
    float hh[3][3];   // half-height [level][aspect]
    float clampv;     // log(224/8)
};

// shared by build_kernel and iou_kernel so proposals match boxes bit-for-bit
__device__ __forceinline__ float4 make_box(float x, float y, float hwv, float hhv,
                                           float4 d, float clampv)
{
    float ax0 = x - hwv, ay0 = y - hhv;
    float ax1 = x + hwv, ay1 = y + hhv;
    float w  = ax1 - ax0, h = ay1 - ay0;
    float cx = (ax0 + ax1) * 0.5f, cy = (ay0 + ay1) * 0.5f;
    float dwx = fminf(d.z, clampv), dwy = fminf(d.w, clampv);
    float ncx = cx + w * d.x, ncy = cy + h * d.y;
    float nw  = w * expf(dwx), nh = h * expf(dwy);
    return make_float4(ncx - 0.5f * nw, ncy - 0.5f * nh,
                       ncx + 0.5f * nw, ncy + 0.5f * nh);
}

__global__ __launch_bounds__(256) void build_kernel(
    const float4* __restrict__ d3,
    const float4* __restrict__ d4,
    const float4* __restrict__ d5,
    float* __restrict__ out,
    BuildConsts C)
{
    int g = blockIdx.x * 256 + threadIdx.x;
    if (g >= NTOT) return;

    int level, a, H, s;
    const float4* dl;
    if (g < 45600)      { level = 0; a = g;         H = 100; s = 8;  dl = d3; }
    else if (g < 57000) { level = 1; a = g - 45600; H = 50;  s = 16; dl = d4; }
    else                { level = 2; a = g - 57000; H = 25;  s = 32; dl = d5; }

    int loc = a / 3;
    int r   = a - loc * 3;
    int i   = loc / H;       // y index
    int j   = loc - i * H;   // x index
    float x = (float)s * ((float)j + 0.5f);
    float y = (float)s * ((float)i + 0.5f);

    float hwv = C.hw[level][r], hhv = C.hh[level][r];
    ((float4*)out)[g] = make_box(x, y, hwv, hhv, dl[a], C.clampv);
    ((float4*)(out + ANCH_OFF))[g] = make_float4(x - hwv, y - hhv, x + hwv, y + hhv);
    out[MIOU_OFF + g] = 0.0f;   // re-zero every call (replays don't re-poison)
}

// grid (59, 32): x covers 59*1024 anchors (4/thread), y = proposal chunk of 64.
// Self-contained: recomputes its 64 proposals from deltas_p3 and its anchors
// from pure index math; culls against the per-chunk proposal bbox.
__global__ __launch_bounds__(256) void iou_kernel(
    const float4* __restrict__ d3,
    float* __restrict__ miou,
    BuildConsts C)
{
    __shared__ float4 Pb[CS];
    __shared__ float  Pa[CS];
    __shared__ float4 bbS;

    int tid = threadIdx.x;

    if (tid < CS) {
        int p = blockIdx.y * CS + tid;
        p = p < NPROP ? p : NPROP - 1;   // clamp: duplicate is harmless for max
        // proposal p == p3 anchor p + deltas_p3[p]
        int loc = p / 3, r = p - loc * 3;
        int i = loc / 100, j = loc - i * 100;
        float x = 8.0f * ((float)j + 0.5f);
        float y = 8.0f * ((float)i + 0.5f);
        float4 b = make_box(x, y, C.hw[0][r], C.hh[0][r], d3[p], C.clampv);
        Pb[tid] = b;
        Pa[tid] = (b.z - b.x) * (b.w - b.y);
        // per-chunk bbox: reduce across this single wave
        float bx0 = b.x, by0 = b.y, bx1 = b.z, by1 = b.w;
        #pragma unroll
        for (int m = 32; m; m >>= 1) {
            bx0 = fminf(bx0, __shfl_xor(bx0, m));
            by0 = fminf(by0, __shfl_xor(by0, m));
            bx1 = fmaxf(bx1, __shfl_xor(bx1, m));
            by1 = fmaxf(by1, __shfl_xor(by1, m));
        }
        if (tid == 0) bbS = make_float4(bx0, by0, bx1, by1);
    }
    __syncthreads();
    float4 bb = bbS;

    int base = blockIdx.x * 1024 + tid;

    float ax0[4], ay0[4], ax1[4], ay1[4], a2[4], Ib[4], Sb[4];
    bool  live[4];
    bool  any = false;
    #pragma unroll
    for (int k = 0; k < 4; ++k) {
        int g = base + k * 256;
        int lev, a, hx;
        float s;
        if (g < 45600)      { lev = 0; a = g;         hx = 100; s = 8.f;  }
        else if (g < 57000) { lev = 1; a = g - 45600; hx = 50;  s = 16.f; }
        else                { lev = 2; a = g - 57000; hx = 25;  s = 32.f; }
        bool valid = (g < NTOT);
        int loc = a / 3, r = a - loc * 3;
        int i = loc / hx, j = loc - i * hx;
        float x = s * ((float)j + 0.5f);
        float y = s * ((float)i + 0.5f);
        float hwv = C.hw[lev][r], hhv = C.hh[lev][r];
        ax0[k] = x - hwv; ay0[k] = y - hhv;
        ax1[k] = x + hwv; ay1[k] = y + hhv;
        a2[k]  = (ax1[k] - ax0[k]) * (ay1[k] - ay0[k]);
        Ib[k]  = 0.0f; Sb[k] = 1.0f;
        live[k] = valid && (ax0[k] <= bb.z) && (ax1[k] >= bb.x)
                        && (ay0[k] <= bb.w) && (ay1[k] >= bb.y);
        any = any || live[k];
    }
    if (!__syncthreads_or((int)any)) return;   // whole block dead

    if (any) {
        #pragma unroll 2
        for (int p = 0; p < CS; ++p) {
            float4 b  = Pb[p];   // broadcast read, conflict-free
            float  pa = Pa[p];
            #pragma unroll
            for (int k = 0; k < 4; ++k) {
                float xl = fmaxf(b.x, ax0[k]);
                float yl = fmaxf(b.y, ay0[k]);
                float xr = fminf(b.z, ax1[k]);
                float yr = fminf(b.w, ay1[k]);
                float iw = fmaxf(xr - xl, 0.0f);
                float ih = fmaxf(yr - yl, 0.0f);
                float inter = iw * ih;
                float S = pa + a2[k];
                // IoU_a > IoU_b  <=>  Ia*Sb > Ib*Sa  (S = sum of areas)
                bool better = inter * Sb[k] > Ib[k] * S;
                Ib[k] = better ? inter : Ib[k];
                Sb[k] = better ? S     : Sb[k];
            }
        }
    }

    #pragma unroll
    for (int k = 0; k < 4; ++k) {
        if (live[k] && Ib[k] > 0.0f) {
            float m = Ib[k] / (Sb[k] - Ib[k]);
            // IoU >= 0: uint compare == float compare; max is order-independent
            atomicMax((unsigned int*)(miou + base + k * 256), __float_as_uint(m));
        }
    }
}

extern "C" void kernel_launch(void* const* d_in, const int* in_sizes, int n_in,
                              void* d_out, int out_size, void* d_ws, size_t ws_size,
                              hipStream_t stream) {
    // inputs: 0..2 = feats (unused), 3..5 = deltas p3/p4/p5
    const float4* d3 = (const float4*)d_in[3];
    const float4* d4 = (const float4*)d_in[4];
    const float4* d5 = (const float4*)d_in[5];
    float* out = (float*)d_out;

    BuildConsts C;
    const double sArr[3]  = {8.0, 16.0, 32.0};
    const double arArr[3] = {0.5, 1.0, 2.0};
    for (int l = 0; l < 3; ++l) {
        double as   = 4.0 * sArr[l];
        double area = as * as;
        for (int rr = 0; rr < 3; ++rr) {
            double w = sqrt(area / arArr[rr]);
            double h = area / w;
            C.hw[l][rr] = (float)w * 0.5f;
            C.hh[l][rr] = (float)h * 0.5f;
        }
    }
    C.clampv = (float)log(224.0 / 8.0);

    build_kernel<<<dim3((NTOT + 255) / 256), 256, 0, stream>>>(d3, d4, d5, out, C);
    // stream order: build zeroes miou before iou's atomics touch it
    iou_kernel<<<dim3(59, NCHUNK), 256, 0, stream>>>(d3, out + MIOU_OFF, C);
}